// Round 5
// baseline (773.731 us; speedup 1.0000x reference)
//
#include <hip/hip_runtime.h>

// Problem constants
#define BATCH 4
#define NSEQ 2048
#define MSEQ 2048
#define DIM 1024
#define HEADS 16
#define DHEAD 64
#define INNER 1024
#define KVLEN 2049          // null token + MSEQ
#define KVPAD 2176          // 17 * 128

typedef unsigned short u16;
typedef unsigned int u32;
typedef __bf16 bf16x8 __attribute__((ext_vector_type(8)));
typedef float f32x4 __attribute__((ext_vector_type(4)));

__device__ inline u16 f2bf(float f) {
  u32 u = __builtin_bit_cast(u32, f);
  u = (u + 0x7fffu + ((u >> 16) & 1u)) >> 16;
  return (u16)u;
}
__device__ inline float bf2f(u16 x) {
  return __builtin_bit_cast(float, (u32)x << 16);
}
// packed bf16 convert: lo -> D[15:0], hi -> D[31:16] (RNE)
__device__ inline u32 pk_bf16(float lo, float hi) {
  u32 r;
  asm("v_cvt_pk_bf16_f32 %0, %1, %2" : "=v"(r) : "v"(lo), "v"(hi));
  return r;
}

__device__ __forceinline__ void gld_lds16(const void* g, void* l) {
  __builtin_amdgcn_global_load_lds(
      (const __attribute__((address_space(1))) void*)g,
      (__attribute__((address_space(3))) void*)l, 16, 0, 0);
}

// ---------------- LayerNorm (row of 1024), output bf16 or fp32 ----------------
template <bool OUT_BF16>
__global__ __launch_bounds__(256) void ln_kernel(const float* __restrict__ x,
                                                 const float* __restrict__ g,
                                                 void* __restrict__ out) {
  const int row = blockIdx.x;
  const int t = threadIdx.x;
  const float4 v = ((const float4*)(x + (size_t)row * 1024))[t];
  float sum = v.x + v.y + v.z + v.w;
  float sq = v.x * v.x + v.y * v.y + v.z * v.z + v.w * v.w;
  for (int m = 1; m < 64; m <<= 1) {
    sum += __shfl_xor(sum, m, 64);
    sq += __shfl_xor(sq, m, 64);
  }
  __shared__ float red[8];
  const int w = t >> 6, l = t & 63;
  if (l == 0) { red[w] = sum; red[4 + w] = sq; }
  __syncthreads();
  sum = red[0] + red[1] + red[2] + red[3];
  sq = red[4] + red[5] + red[6] + red[7];
  const float mean = sum * (1.0f / 1024.0f);
  const float var = sq * (1.0f / 1024.0f) - mean * mean;
  const float rstd = rsqrtf(var + 1e-5f);
  const float4 gv = ((const float4*)g)[t];
  float o0 = (v.x - mean) * rstd * gv.x;
  float o1 = (v.y - mean) * rstd * gv.y;
  float o2 = (v.z - mean) * rstd * gv.z;
  float o3 = (v.w - mean) * rstd * gv.w;
  if (OUT_BF16) {
    ushort4 ov;
    ov.x = f2bf(o0); ov.y = f2bf(o1); ov.z = f2bf(o2); ov.w = f2bf(o3);
    ((ushort4*)((u16*)out + (size_t)row * 1024))[t] = ov;
  } else {
    float4 ov;
    ov.x = o0; ov.y = o1; ov.z = o2; ov.w = o3;
    ((float4*)((float*)out + (size_t)row * 1024))[t] = ov;
  }
}

// ---------------- fp32 -> bf16 cast (vectorized by 4) ----------------
__global__ __launch_bounds__(256) void cast_bf16(const float* __restrict__ in,
                                                 u16* __restrict__ out, int n4) {
  int i = blockIdx.x * 256 + threadIdx.x;
  if (i < n4) {
    float4 v = ((const float4*)in)[i];
    ushort4 o;
    o.x = f2bf(v.x); o.y = f2bf(v.y); o.z = f2bf(v.z); o.w = f2bf(v.w);
    ((ushort4*)out)[i] = o;
  }
}

// ---------------- W[K][N] fp32 -> WT[N][K] bf16 (tiled transpose) ----------------
__global__ __launch_bounds__(256) void transpose_cast(const float* __restrict__ W,
                                                      u16* __restrict__ WT, int K, int N) {
  __shared__ float tile[32][33];
  const int tx = threadIdx.x & 31, ty = threadIdx.x >> 5;  // ty 0..7
  const int k0 = blockIdx.y * 32, n0 = blockIdx.x * 32;
  for (int r = ty; r < 32; r += 8) tile[r][tx] = W[(size_t)(k0 + r) * N + n0 + tx];
  __syncthreads();
  for (int r = ty; r < 32; r += 8) WT[(size_t)(n0 + r) * K + k0 + tx] = f2bf(tile[tx][r]);
}

// ---------------- bf16 GEMM: C = A[M][K] @ Bt[N][K]^T ----------------
// MODE 0: fp32 C row-major. MODE 1: bf16 C row-major.
// MODE 2: fused q_post -> l2norm(head)*scale*8, write qn[b,h,n,64].
// MODE 3: fused kv post -> heads 0..15: l2norm*k_scale -> kn[b,h,m+1,64];
//                          heads 16..31: plain bf16 -> aux[row][ (h-16)*64+d ].
template <int MODE>
__global__ __launch_bounds__(256) void gemm_bt(const u16* __restrict__ A,
                                               const u16* __restrict__ Bt,
                                               void* __restrict__ Cv,
                                               int M, int N, int K,
                                               const float* __restrict__ scale,
                                               u16* __restrict__ aux) {
  __shared__ __align__(16) u16 As[128 * 32];
  __shared__ __align__(16) u16 Bs[128 * 32];
  const int t = threadIdx.x;
  const int w = t >> 6, l = t & 63, l15 = l & 15, lq = l >> 4;
  const int m0 = blockIdx.y * 128, n0 = blockIdx.x * 128;
  const int wm = (w >> 1) * 64, wn = (w & 1) * 64;
  const int lr = l >> 2;           // 0..15 row-within-chunk
  const int lo = (l & 3) * 8;      // u16 offset within row: 0,8,16,24
  f32x4 acc[4][4] = {};
  for (int k0 = 0; k0 < K; k0 += 32) {
#pragma unroll
    for (int it = 0; it < 2; it++) {
      const int row = (w * 2 + it) * 16 + lr;   // 0..127
      gld_lds16(&A[(size_t)(m0 + row) * K + k0 + lo], &As[row * 32 + lo]);
      gld_lds16(&Bt[(size_t)(n0 + row) * K + k0 + lo], &Bs[row * 32 + lo]);
    }
    __syncthreads();
    bf16x8 af[4], bfr[4];
#pragma unroll
    for (int i = 0; i < 4; i++) af[i] = *(bf16x8*)&As[(wm + i * 16 + l15) * 32 + lq * 8];
#pragma unroll
    for (int j = 0; j < 4; j++) bfr[j] = *(bf16x8*)&Bs[(wn + j * 16 + l15) * 32 + lq * 8];
#pragma unroll
    for (int i = 0; i < 4; i++)
#pragma unroll
      for (int j = 0; j < 4; j++)
        acc[i][j] = __builtin_amdgcn_mfma_f32_16x16x32_bf16(af[i], bfr[j], acc[i][j], 0, 0, 0);
    __syncthreads();
  }

  if (MODE <= 1) {
#pragma unroll
    for (int i = 0; i < 4; i++)
#pragma unroll
      for (int j = 0; j < 4; j++)
#pragma unroll
        for (int r = 0; r < 4; r++) {
          const size_t off =
              (size_t)(m0 + wm + i * 16 + lq * 4 + r) * N + n0 + wn + j * 16 + l15;
          if (MODE == 1) ((u16*)Cv)[off] = f2bf(acc[i][j][r]);
          else ((float*)Cv)[off] = acc[i][j][r];
        }
    return;
  }

  const int head = (n0 + wn) >> 6;  // wave-uniform
  if (MODE == 3 && head >= 16) {
    // V columns: plain bf16 into compact aux[row][ (head-16)*64 + d ]
#pragma unroll
    for (int i = 0; i < 4; i++)
#pragma unroll
      for (int j = 0; j < 4; j++)
#pragma unroll
        for (int r = 0; r < 4; r++) {
          const int row = m0 + wm + i * 16 + lq * 4 + r;
          aux[(size_t)row * 1024 + (head - 16) * 64 + j * 16 + l15] = f2bf(acc[i][j][r]);
        }
    return;
  }
  // l2norm over the 64-col head + scale (q: *8)
  float sc[4];
#pragma unroll
  for (int j = 0; j < 4; j++) sc[j] = scale[j * 16 + l15];
  const float mul = (MODE == 2) ? 8.0f : 1.0f;
  u16* outp = (u16*)Cv;
#pragma unroll
  for (int i = 0; i < 4; i++)
#pragma unroll
    for (int r = 0; r < 4; r++) {
      float ss = 0.f;
#pragma unroll
      for (int j = 0; j < 4; j++) ss = fmaf(acc[i][j][r], acc[i][j][r], ss);
#pragma unroll
      for (int m = 1; m < 16; m <<= 1) ss += __shfl_xor(ss, m, 64);
      const float inv = mul / fmaxf(sqrtf(ss), 1e-12f);
      const int row = m0 + wm + i * 16 + lq * 4 + r;
      const int b = row >> 11, n = row & 2047;
      const size_t base = (MODE == 2)
          ? (((size_t)b * 16 + head) * 2048 + n) * 64
          : (((size_t)b * 16 + head) * (size_t)KVPAD + n + 1) * 64;
#pragma unroll
      for (int j = 0; j < 4; j++)
        outp[base + j * 16 + l15] = f2bf(acc[i][j][r] * inv * sc[j]);
    }
}

// ---------------- v post: transpose vg[row][h*64+d] -> vt[b,h,64,KVPAD] ----------------
// The KV (column) index is stored k-PERMUTED within each 128-aligned block:
//   slot(abs) = (abs & ~127) | ((abs & 15) << 3) | ((abs >> 4) & 7)
// This matches the packed P layout in attn_kernel (PV contraction is invariant
// under a shared k-permutation). pi(0)=0 and pi fixes {1..127}, so null_tail
// (null token at slot 0, tail zeroing of 2049..2175) needs no change.
__global__ __launch_bounds__(256) void v_post(const u16* __restrict__ vg,
                                              u16* __restrict__ vt) {
  __shared__ u16 tile[64][68];
  const int bh = blockIdx.y, mt = blockIdx.x;
  const int tx = threadIdx.x & 63, ty = threadIdx.x >> 6;
  const int b = bh >> 4, h = bh & 15;
  const int m0 = mt * 64;
  for (int r = ty; r < 64; r += 4)
    tile[tx][r] = vg[(size_t)(b * 2048 + m0 + r) * 1024 + h * 64 + tx];
  __syncthreads();
  const int abs_ = 1 + m0 + tx;
  const int slot = (abs_ & ~127) | ((abs_ & 15) << 3) | ((abs_ >> 4) & 7);
  for (int d = ty; d < 64; d += 4)
    vt[((size_t)bh * 64 + d) * KVPAD + slot] = tile[d][tx];
}

// ---------------- null token + tail zeroing (R5: tail loops parallelized over 256 threads) ----------------
__global__ __launch_bounds__(256) void null_tail(const float* __restrict__ null_kv,
                                                 const float* __restrict__ k_scale,
                                                 u16* __restrict__ kn, u16* __restrict__ vt) {
  const int bh = blockIdx.x, t = threadIdx.x;
  const int d = t & 63, seg = t >> 6;  // seg 0..3
  if (seg == 0) {  // one full wave: null token (needs 64-lane reduction)
    float nk = null_kv[d];
    float nv = null_kv[64 + d];
    float ss = nk * nk;
    for (int m = 1; m < 64; m <<= 1) ss += __shfl_xor(ss, m, 64);
    float inv = 1.0f / fmaxf(sqrtf(ss), 1e-12f);
    kn[((size_t)bh * KVPAD) * 64 + d] = f2bf(nk * inv * k_scale[d]);
    vt[((size_t)bh * 64 + d) * KVPAD] = f2bf(nv);  // slot(0) == 0
  }
  for (int m = KVLEN + seg; m < KVPAD; m += 4) kn[((size_t)bh * KVPAD + m) * 64 + d] = 0;
  u16* vrow = vt + ((size_t)bh * 64 + d) * KVPAD;
  for (int m = KVLEN + seg; m < KVPAD; m += 4) vrow[m] = 0;
}

// ---------------- flash attention, fixed-max softmax ----------------
// |sim| <= 8 by Cauchy-Schwarz (l2norm'd q,k; scales==1; SCALE=8) -> static max 8.
// R5: NO K/V LDS staging. R4's counters close on LDS-instr throughput (~192
// wave LDS instrs/block-kt ~= 2300 cyc ~= the whole 134us), while K/V tiles
// (16KB each) are L1/L2-resident (Common-mistake #7: staging L2-fit data is
// pure overhead). K and V MFMA fragments are read DIRECTLY from global:
//   bk(kt,j,ks)  = kn[bh*KVPAD*64 + kt*8192 + (j*16+l15)*64 + ks*32 + lq*8]
//   bv(kt,nt,ks) = vt[(bh*64 + nt*16+l15)*KVPAD + kt*128 + ks*32 + lq*8]
// (derived by composing R4's staging map with its LDS fragment reads).
// Only the P tile lives in LDS (wave-private rows, dedicated buffer) -> the
// kernel is barrier-free; LDS instrs/block-kt drop 192 -> 32.
// P stored k-PERMUTED (pi(c) = (c&15)*8 + (c>>4) within each 128-block): one
// ds_write_b128 per fragment row via v_cvt_pk_bf16_f32; V^T global layout
// carries the same permutation (see v_post), so PV indices are unchanged.
// P-write -> P-read hand-off: same-wave, no barrier (R1/R4-proven pattern,
// kept byte-identical: uint4 store, bf16x8 load).
__global__ __launch_bounds__(256, 4) void attn_kernel(const u16* __restrict__ qn,
                                                      const u16* __restrict__ kn,
                                                      const u16* __restrict__ vt,
                                                      u16* __restrict__ aout) {
  __shared__ __align__(16) u16 Ps[64 * 136];  // P tile only, stride 136
  const int qt = blockIdx.x, bh = blockIdx.y;
  const int b = bh >> 4, h = bh & 15;
  const int t = threadIdx.x, w = t >> 6, l = t & 63, l15 = l & 15, lq = l >> 4;

  // Q fragments straight from global (loop-invariant)
  bf16x8 aqf[2];
  {
    const u16* qrow = qn + ((size_t)bh * 2048 + qt * 64 + w * 16 + l15) * 64 + lq * 8;
    aqf[0] = *(const bf16x8*)(qrow);
    aqf[1] = *(const bf16x8*)(qrow + 32);
  }

  // per-lane K/V fragment base pointers
  const u16* kptr = kn + (size_t)bh * KVPAD * 64 + l15 * 64 + lq * 8;
  const u16* vptr = vt + ((size_t)bh * 64 + l15) * KVPAD + lq * 8;

  f32x4 O[4] = {};
  float lsum[4] = {0.f, 0.f, 0.f, 0.f};
  const float LOG2E = 1.44269504f;
  const float MBIAS = -8.0f * 1.44269504f;  // exp(s-8) = 2^(s*log2e + MBIAS)

  for (int kt = 0; kt < 17; kt++) {
    // ---- S = Q K^T, K fragments direct from global (L1/L2-served) ----
    f32x4 S[8] = {};
    __builtin_amdgcn_s_setprio(1);
#pragma unroll
    for (int ks = 0; ks < 2; ks++)
#pragma unroll
      for (int j = 0; j < 8; j++) {
        bf16x8 bk = *(const bf16x8*)(kptr + kt * 8192 + j * 1024 + ks * 32);
        S[j] = __builtin_amdgcn_mfma_f32_16x16x32_bf16(aqf[ks], bk, S[j], 0, 0, 0);
      }
    __builtin_amdgcn_s_setprio(0);

    // ---- P = exp(S - 8), accumulate row sums; pack + b128-write permuted P ----
    const bool last = (kt == 16);
#pragma unroll
    for (int r = 0; r < 4; r++) {
      float pe[8];
#pragma unroll
      for (int j = 0; j < 8; j++) {
        float p = __builtin_amdgcn_exp2f(fmaf(S[j][r], LOG2E, MBIAS));
        if (last && ((j << 4) | l15) != 0) p = 0.f;  // only global col 2048 valid
        lsum[r] += p;
        pe[j] = p;
      }
      uint4 pw;
      pw.x = pk_bf16(pe[0], pe[1]);
      pw.y = pk_bf16(pe[2], pe[3]);
      pw.z = pk_bf16(pe[4], pe[5]);
      pw.w = pk_bf16(pe[6], pe[7]);
      // row (w*16+lq*4+r), permuted cols l15*8 .. l15*8+7 -> byte row*272 + l15*16
      *(uint4*)&Ps[(w * 16 + lq * 4 + r) * 136 + l15 * 8] = pw;
    }
    // no barrier: wave reads back only its own P rows

    // ---- O += P V, V fragments direct from global (permuted k-order) ----
    __builtin_amdgcn_s_setprio(1);
#pragma unroll
    for (int ks = 0; ks < 4; ks++) {
      bf16x8 ap = *(bf16x8*)&Ps[(w * 16 + l15) * 136 + ks * 32 + lq * 8];
#pragma unroll
      for (int nt = 0; nt < 4; nt++) {
        bf16x8 bv = *(const bf16x8*)(vptr + (size_t)nt * 16 * KVPAD + kt * 128 + ks * 32);
        O[nt] = __builtin_amdgcn_mfma_f32_16x16x32_bf16(ap, bv, O[nt], 0, 0, 0);
      }
    }
    __builtin_amdgcn_s_setprio(0);
  }

  // ---- final row-sum reduction (once per block) + normalize + store ----
#pragma unroll
  for (int r = 0; r < 4; r++)
#pragma unroll
    for (int m = 1; m < 16; m <<= 1) lsum[r] += __shfl_xor(lsum[r], m, 64);
#pragma unroll
  for (int nt = 0; nt < 4; nt++)
#pragma unroll
    for (int r = 0; r < 4; r++) {
      int row = qt * 64 + w * 16 + lq * 4 + r;
      int col = h * 64 + nt * 16 + l15;
      float val = O[nt][r] / lsum[r];
      aout[((size_t)b * 2048 + row) * 1024 + col] = f2bf(val);
    }
}

// ---------------- host launch ----------------
extern "C" void kernel_launch(void* const* d_in, const int* in_sizes, int n_in,
                              void* d_out, int out_size, void* d_ws, size_t ws_size,
                              hipStream_t stream) {
  const float* x = (const float*)d_in[0];
  const float* context = (const float*)d_in[1];
  const float* g_norm = (const float*)d_in[2];
  const float* null_kv = (const float*)d_in[3];
  const float* Wq = (const float*)d_in[4];
  const float* Wkv = (const float*)d_in[5];
  const float* q_scale = (const float*)d_in[6];
  const float* k_scale = (const float*)d_in[7];
  const float* Wout = (const float*)d_in[8];
  const float* g_out = (const float*)d_in[9];
  float* out = (float*)d_out;

  char* ws = (char*)d_ws;
  u16* xn = (u16*)(ws);                      // 16,777,216 B
  u16* ctxb = (u16*)(ws + 16777216);         // 16,777,216
  u16* wqT = (u16*)(ws + 33554432);          // 2,097,152
  u16* wkvT = (u16*)(ws + 35651584);         // 4,194,304
  u16* woutT = (u16*)(ws + 39845888);        // 2,097,152
  u16* qnb = (u16*)(ws + 41943040);          // 16,777,216
  u16* knb = (u16*)(ws + 58720256);          // 17,825,792
  u16* vtb = (u16*)(ws + 76546048);          // 17,825,792
  u16* vg = (u16*)(ws + 94371840);           // 16,777,216
  float* outg = (float*)(ws + 111149056);    // 33,554,432 -> total 144,703,488
  u16* attn_out = vg;                        // vg fully consumed by v_post

  ln_kernel<true><<<8192, 256, 0, stream>>>(x, g_norm, xn);
  cast_bf16<<<8192, 256, 0, stream>>>(context, ctxb, 2097152);
  transpose_cast<<<dim3(32, 32), 256, 0, stream>>>(Wq, wqT, 1024, 1024);
  transpose_cast<<<dim3(64, 32), 256, 0, stream>>>(Wkv, wkvT, 1024, 2048);
  transpose_cast<<<dim3(32, 32), 256, 0, stream>>>(Wout, woutT, 1024, 1024);
  gemm_bt<2><<<dim3(8, 64), 256, 0, stream>>>(xn, wqT, qnb, 8192, 1024, 1024, q_scale, nullptr);
  gemm_bt<3><<<dim3(16, 64), 256, 0, stream>>>(ctxb, wkvT, knb, 8192, 2048, 1024, k_scale, vg);
  v_post<<<dim3(32, 64), 256, 0, stream>>>(vg, vtb);
  null_tail<<<64, 256, 0, stream>>>(null_kv, k_scale, knb, vtb);
  attn_kernel<<<dim3(32, 64), 256, 0, stream>>>(qnb, knb, vtb, attn_out);
  gemm_bt<0><<<dim3(8, 64), 256, 0, stream>>>(attn_out, woutT, outg, 8192, 1024, 1024, nullptr, nullptr);
  ln_kernel<false><<<8192, 256, 0, stream>>>(outg, g_out, out);
}

// Round 6
// 420.415 us; speedup vs baseline: 1.8404x; 1.8404x over previous
//
#include <hip/hip_runtime.h>

// Problem constants
#define BATCH 4
#define NSEQ 2048
#define MSEQ 2048
#define DIM 1024
#define HEADS 16
#define DHEAD 64
#define INNER 1024
#define KVLEN 2049          // null token + MSEQ
#define KVPAD 2176          // 17 * 128

typedef unsigned short u16;
typedef unsigned int u32;
typedef __bf16 bf16x8 __attribute__((ext_vector_type(8)));
typedef float f32x4 __attribute__((ext_vector_type(4)));

__device__ inline u16 f2bf(float f) {
  u32 u = __builtin_bit_cast(u32, f);
  u = (u + 0x7fffu + ((u >> 16) & 1u)) >> 16;
  return (u16)u;
}
__device__ inline float bf2f(u16 x) {
  return __builtin_bit_cast(float, (u32)x << 16);
}
// packed bf16 convert: lo -> D[15:0], hi -> D[31:16] (RNE)
__device__ inline u32 pk_bf16(float lo, float hi) {
  u32 r;
  asm("v_cvt_pk_bf16_f32 %0, %1, %2" : "=v"(r) : "v"(lo), "v"(hi));
  return r;
}

__device__ __forceinline__ void gld_lds16(const void* g, void* l) {
  __builtin_amdgcn_global_load_lds(
      (const __attribute__((address_space(1))) void*)g,
      (__attribute__((address_space(3))) void*)l, 16, 0, 0);
}

// ---------------- LayerNorm (row of 1024), output bf16 or fp32 ----------------
template <bool OUT_BF16>
__global__ __launch_bounds__(256) void ln_kernel(const float* __restrict__ x,
                                                 const float* __restrict__ g,
                                                 void* __restrict__ out) {
  const int row = blockIdx.x;
  const int t = threadIdx.x;
  const float4 v = ((const float4*)(x + (size_t)row * 1024))[t];
  float sum = v.x + v.y + v.z + v.w;
  float sq = v.x * v.x + v.y * v.y + v.z * v.z + v.w * v.w;
  for (int m = 1; m < 64; m <<= 1) {
    sum += __shfl_xor(sum, m, 64);
    sq += __shfl_xor(sq, m, 64);
  }
  __shared__ float red[8];
  const int w = t >> 6, l = t & 63;
  if (l == 0) { red[w] = sum; red[4 + w] = sq; }
  __syncthreads();
  sum = red[0] + red[1] + red[2] + red[3];
  sq = red[4] + red[5] + red[6] + red[7];
  const float mean = sum * (1.0f / 1024.0f);
  const float var = sq * (1.0f / 1024.0f) - mean * mean;
  const float rstd = rsqrtf(var + 1e-5f);
  const float4 gv = ((const float4*)g)[t];
  float o0 = (v.x - mean) * rstd * gv.x;
  float o1 = (v.y - mean) * rstd * gv.y;
  float o2 = (v.z - mean) * rstd * gv.z;
  float o3 = (v.w - mean) * rstd * gv.w;
  if (OUT_BF16) {
    ushort4 ov;
    ov.x = f2bf(o0); ov.y = f2bf(o1); ov.z = f2bf(o2); ov.w = f2bf(o3);
    ((ushort4*)((u16*)out + (size_t)row * 1024))[t] = ov;
  } else {
    float4 ov;
    ov.x = o0; ov.y = o1; ov.z = o2; ov.w = o3;
    ((float4*)((float*)out + (size_t)row * 1024))[t] = ov;
  }
}

// ---------------- fp32 -> bf16 cast (vectorized by 4) ----------------
__global__ __launch_bounds__(256) void cast_bf16(const float* __restrict__ in,
                                                 u16* __restrict__ out, int n4) {
  int i = blockIdx.x * 256 + threadIdx.x;
  if (i < n4) {
    float4 v = ((const float4*)in)[i];
    ushort4 o;
    o.x = f2bf(v.x); o.y = f2bf(v.y); o.z = f2bf(v.z); o.w = f2bf(v.w);
    ((ushort4*)out)[i] = o;
  }
}

// ---------------- W[K][N] fp32 -> WT[N][K] bf16 (tiled transpose) ----------------
__global__ __launch_bounds__(256) void transpose_cast(const float* __restrict__ W,
                                                      u16* __restrict__ WT, int K, int N) {
  __shared__ float tile[32][33];
  const int tx = threadIdx.x & 31, ty = threadIdx.x >> 5;  // ty 0..7
  const int k0 = blockIdx.y * 32, n0 = blockIdx.x * 32;
  for (int r = ty; r < 32; r += 8) tile[r][tx] = W[(size_t)(k0 + r) * N + n0 + tx];
  __syncthreads();
  for (int r = ty; r < 32; r += 8) WT[(size_t)(n0 + r) * K + k0 + tx] = f2bf(tile[tx][r]);
}

// ---------------- bf16 GEMM: C = A[M][K] @ Bt[N][K]^T ----------------
// MODE 0: fp32 C row-major. MODE 1: bf16 C row-major.
// MODE 2: fused q_post -> l2norm(head)*scale*8, write qn[b,h,n,64].
// MODE 3: fused kv post -> heads 0..15: l2norm*k_scale -> kn[b,h,m+1,64];
//                          heads 16..31: plain bf16 -> aux[row][ (h-16)*64+d ].
template <int MODE>
__global__ __launch_bounds__(256) void gemm_bt(const u16* __restrict__ A,
                                               const u16* __restrict__ Bt,
                                               void* __restrict__ Cv,
                                               int M, int N, int K,
                                               const float* __restrict__ scale,
                                               u16* __restrict__ aux) {
  __shared__ __align__(16) u16 As[128 * 32];
  __shared__ __align__(16) u16 Bs[128 * 32];
  const int t = threadIdx.x;
  const int w = t >> 6, l = t & 63, l15 = l & 15, lq = l >> 4;
  const int m0 = blockIdx.y * 128, n0 = blockIdx.x * 128;
  const int wm = (w >> 1) * 64, wn = (w & 1) * 64;
  const int lr = l >> 2;           // 0..15 row-within-chunk
  const int lo = (l & 3) * 8;      // u16 offset within row: 0,8,16,24
  f32x4 acc[4][4] = {};
  for (int k0 = 0; k0 < K; k0 += 32) {
#pragma unroll
    for (int it = 0; it < 2; it++) {
      const int row = (w * 2 + it) * 16 + lr;   // 0..127
      gld_lds16(&A[(size_t)(m0 + row) * K + k0 + lo], &As[row * 32 + lo]);
      gld_lds16(&Bt[(size_t)(n0 + row) * K + k0 + lo], &Bs[row * 32 + lo]);
    }
    __syncthreads();
    bf16x8 af[4], bfr[4];
#pragma unroll
    for (int i = 0; i < 4; i++) af[i] = *(bf16x8*)&As[(wm + i * 16 + l15) * 32 + lq * 8];
#pragma unroll
    for (int j = 0; j < 4; j++) bfr[j] = *(bf16x8*)&Bs[(wn + j * 16 + l15) * 32 + lq * 8];
#pragma unroll
    for (int i = 0; i < 4; i++)
#pragma unroll
      for (int j = 0; j < 4; j++)
        acc[i][j] = __builtin_amdgcn_mfma_f32_16x16x32_bf16(af[i], bfr[j], acc[i][j], 0, 0, 0);
    __syncthreads();
  }

  if (MODE <= 1) {
#pragma unroll
    for (int i = 0; i < 4; i++)
#pragma unroll
      for (int j = 0; j < 4; j++)
#pragma unroll
        for (int r = 0; r < 4; r++) {
          const size_t off =
              (size_t)(m0 + wm + i * 16 + lq * 4 + r) * N + n0 + wn + j * 16 + l15;
          if (MODE == 1) ((u16*)Cv)[off] = f2bf(acc[i][j][r]);
          else ((float*)Cv)[off] = acc[i][j][r];
        }
    return;
  }

  const int head = (n0 + wn) >> 6;  // wave-uniform
  if (MODE == 3 && head >= 16) {
    // V columns: plain bf16 into compact aux[row][ (head-16)*64 + d ]
#pragma unroll
    for (int i = 0; i < 4; i++)
#pragma unroll
      for (int j = 0; j < 4; j++)
#pragma unroll
        for (int r = 0; r < 4; r++) {
          const int row = m0 + wm + i * 16 + lq * 4 + r;
          aux[(size_t)row * 1024 + (head - 16) * 64 + j * 16 + l15] = f2bf(acc[i][j][r]);
        }
    return;
  }
  // l2norm over the 64-col head + scale (q: *8)
  float sc[4];
#pragma unroll
  for (int j = 0; j < 4; j++) sc[j] = scale[j * 16 + l15];
  const float mul = (MODE == 2) ? 8.0f : 1.0f;
  u16* outp = (u16*)Cv;
#pragma unroll
  for (int i = 0; i < 4; i++)
#pragma unroll
    for (int r = 0; r < 4; r++) {
      float ss = 0.f;
#pragma unroll
      for (int j = 0; j < 4; j++) ss = fmaf(acc[i][j][r], acc[i][j][r], ss);
#pragma unroll
      for (int m = 1; m < 16; m <<= 1) ss += __shfl_xor(ss, m, 64);
      const float inv = mul / fmaxf(sqrtf(ss), 1e-12f);
      const int row = m0 + wm + i * 16 + lq * 4 + r;
      const int b = row >> 11, n = row & 2047;
      const size_t base = (MODE == 2)
          ? (((size_t)b * 16 + head) * 2048 + n) * 64
          : (((size_t)b * 16 + head) * (size_t)KVPAD + n + 1) * 64;
#pragma unroll
      for (int j = 0; j < 4; j++)
        outp[base + j * 16 + l15] = f2bf(acc[i][j][r] * inv * sc[j]);
    }
}

// ---------------- v post: transpose vg[row][h*64+d] -> vt[b,h,64,KVPAD] ----------------
// The KV (column) index is stored k-PERMUTED within each 128-aligned block:
//   slot(abs) = (abs & ~127) | ((abs & 15) << 3) | ((abs >> 4) & 7)
// This matches the packed P layout in attn_kernel (PV contraction is invariant
// under a shared k-permutation). pi(0)=0 and pi maps {1..127} onto {1..127},
// so null_tail (null token at slot 0, tail zeroing of 2049..2175) is unchanged.
__global__ __launch_bounds__(256) void v_post(const u16* __restrict__ vg,
                                              u16* __restrict__ vt) {
  __shared__ u16 tile[64][68];
  const int bh = blockIdx.y, mt = blockIdx.x;
  const int tx = threadIdx.x & 63, ty = threadIdx.x >> 6;
  const int b = bh >> 4, h = bh & 15;
  const int m0 = mt * 64;
  for (int r = ty; r < 64; r += 4)
    tile[tx][r] = vg[(size_t)(b * 2048 + m0 + r) * 1024 + h * 64 + tx];
  __syncthreads();
  const int abs_ = 1 + m0 + tx;
  const int slot = (abs_ & ~127) | ((abs_ & 15) << 3) | ((abs_ >> 4) & 7);
  for (int d = ty; d < 64; d += 4)
    vt[((size_t)bh * 64 + d) * KVPAD + slot] = tile[d][tx];
}

// ---------------- null token + tail zeroing (256-thread version, R5-verified) ----------------
__global__ __launch_bounds__(256) void null_tail(const float* __restrict__ null_kv,
                                                 const float* __restrict__ k_scale,
                                                 u16* __restrict__ kn, u16* __restrict__ vt) {
  const int bh = blockIdx.x, t = threadIdx.x;
  const int d = t & 63, seg = t >> 6;  // seg 0..3
  if (seg == 0) {  // one full wave: null token (needs 64-lane reduction)
    float nk = null_kv[d];
    float nv = null_kv[64 + d];
    float ss = nk * nk;
    for (int m = 1; m < 64; m <<= 1) ss += __shfl_xor(ss, m, 64);
    float inv = 1.0f / fmaxf(sqrtf(ss), 1e-12f);
    kn[((size_t)bh * KVPAD) * 64 + d] = f2bf(nk * inv * k_scale[d]);
    vt[((size_t)bh * 64 + d) * KVPAD] = f2bf(nv);  // slot(0) == 0
  }
  for (int m = KVLEN + seg; m < KVPAD; m += 4) kn[((size_t)bh * KVPAD + m) * 64 + d] = 0;
  u16* vrow = vt + ((size_t)bh * 64 + d) * KVPAD;
  for (int m = KVLEN + seg; m < KVPAD; m += 4) vrow[m] = 0;
}

// ---------------- flash attention, fixed-max softmax ----------------
// |sim| <= 8 by Cauchy-Schwarz (l2norm'd q,k; scales==1; SCALE=8) -> static max 8.
// R6: R4's proven structure (64 q-rows/block, 16/wave, 17 KV tiles of 128),
// staging switched to global_load_lds (no VGPR round-trip, no ds_write issue):
//   - LDS K [128][64] u16 and V [64][128] u16 are LINEAR (gld_lds requirement).
//   - Bank conflicts avoided by SOURCE-side swizzle (m173/T2 both-sides rule):
//     LDS[row][slot16'] holds global slot16 s = s' ^ (row&7); every fragment
//     read applies the same XOR: slot' = (ks*4+lq) ^ (l15&7). All access
//     patterns land at 2-way/16-lane-phase = free (m136). Producers untouched.
//   - P tile overwrites the K buffer as a [64][128] swizzled view (16 KB,
//     exact fit); P write slot' = l15 ^ (prow&7). Same-wave P-write->ap-read
//     hand-off byte-identical to R4 (uint4 store / bf16x8 load, no barrier).
// LDS 32768 B -> 4 blocks/CU. s_setprio around MFMA clusters (R4-banked T5).
// R5 post-mortem: NO-staging (direct-global fragments) is 3.6x WORSE (489us) —
// lane-strided fragment reads splinter into 16 cache-line transactions/load.
// R2/R3 post-mortem: 32-q-rows/wave variant fails correctness (unlocalized);
// do not re-attempt without single-delta bisection.
__global__ __launch_bounds__(256, 4) void attn_kernel(const u16* __restrict__ qn,
                                                      const u16* __restrict__ kn,
                                                      const u16* __restrict__ vt,
                                                      u16* __restrict__ aout) {
  __shared__ __align__(16) u16 Ks[128 * 64];  // K tile (linear, src-swizzled) / P tile [64][128]
  __shared__ __align__(16) u16 Vs[64 * 128];  // V^T tile (linear, src-swizzled)
  const int qt = blockIdx.x, bh = blockIdx.y;
  const int b = bh >> 4, h = bh & 15;
  const int t = threadIdx.x, w = t >> 6, l = t & 63, l15 = l & 15, lq = l >> 4;

  // Q fragments straight from global (loop-invariant)
  bf16x8 aqf[2];
  {
    const u16* qrow = qn + ((size_t)bh * 2048 + qt * 64 + w * 16 + l15) * 64 + lq * 8;
    aqf[0] = *(const bf16x8*)(qrow);
    aqf[1] = *(const bf16x8*)(qrow + 32);
  }

  // swizzled fragment-read slot offsets (u16): slot' = (ks*4+lq) ^ (l15&7)
  int so[4];
#pragma unroll
  for (int ks = 0; ks < 4; ks++) so[ks] = ((ks * 4 + lq) ^ (l15 & 7)) * 8;

  // staging: per-lane swizzled GLOBAL source, linear LDS dest (base + lane*16)
  const u16* kn_b = kn + (size_t)bh * KVPAD * 64;
  const u16* vt_b = vt + (size_t)bh * 64 * KVPAD;
  const u16* ksrc[4];
  const u16* vsrc[4];
#pragma unroll
  for (int i = 0; i < 4; i++) {
    const int rk = (w * 4 + i) * 8 + (l >> 3);        // K row 0..127
    const int sk = (l & 7) ^ ((l >> 3) & 7);          // swizzled 16B slot (rk&7 == (l>>3)&7)
    ksrc[i] = kn_b + rk * 64 + sk * 8;
    const int rd = (w * 4 + i) * 4 + (l >> 4);        // V d-row 0..63
    const int sv = (l & 15) ^ (rd & 7);               // swizzled 16B slot
    vsrc[i] = vt_b + (size_t)rd * KVPAD + sv * 8;
  }
  u16* kdst = &Ks[w * 2048 + l * 8];  // (w*4+i)*512 + l*8, i via +i*512
  u16* vdst = &Vs[w * 2048 + l * 8];

  f32x4 O[4] = {};
  float lsum[4] = {0.f, 0.f, 0.f, 0.f};
  const float LOG2E = 1.44269504f;
  const float MBIAS = -8.0f * 1.44269504f;  // exp(s-8) = 2^(s*log2e + MBIAS)

  for (int kt = 0; kt < 17; kt++) {
    // ---- stage K (128x64) and V^T (64x128) via global_load_lds, src-swizzled ----
#pragma unroll
    for (int i = 0; i < 4; i++) {
      gld_lds16(ksrc[i] + kt * 8192, kdst + i * 512);
      gld_lds16(vsrc[i] + kt * 128, vdst + i * 512);
    }
    __syncthreads();  // compiler drains vmcnt before s_barrier

    // ---- S = Q K^T (wave w owns q rows w*16..w*16+15) ----
    f32x4 S[8] = {};
    __builtin_amdgcn_s_setprio(1);
#pragma unroll
    for (int ks = 0; ks < 2; ks++)
#pragma unroll
      for (int j = 0; j < 8; j++) {
        bf16x8 bk = *(bf16x8*)&Ks[(j * 16 + l15) * 64 + so[ks]];
        S[j] = __builtin_amdgcn_mfma_f32_16x16x32_bf16(aqf[ks], bk, S[j], 0, 0, 0);
      }
    __builtin_amdgcn_s_setprio(0);
    __syncthreads();  // all waves done reading K before P overwrites it

    // ---- P = exp(S - 8), accumulate row sums; pack + b128-write swizzled P ----
    const bool last = (kt == 16);
#pragma unroll
    for (int r = 0; r < 4; r++) {
      float pe[8];
#pragma unroll
      for (int j = 0; j < 8; j++) {
        float p = __builtin_amdgcn_exp2f(fmaf(S[j][r], LOG2E, MBIAS));
        if (last && ((j << 4) | l15) != 0) p = 0.f;  // only global col 2048 valid
        lsum[r] += p;
        pe[j] = p;
      }
      uint4 pw;
      pw.x = pk_bf16(pe[0], pe[1]);
      pw.y = pk_bf16(pe[2], pe[3]);
      pw.z = pk_bf16(pe[4], pe[5]);
      pw.w = pk_bf16(pe[6], pe[7]);
      // P row (w*16+lq*4+r), slot16 l15 -> swizzled slot l15 ^ (prow&7)
      const int prow = w * 16 + lq * 4 + r;
      *(uint4*)&Ks[prow * 128 + ((l15 ^ (prow & 7)) * 8)] = pw;
    }
    // no barrier: wave reads back only its own P rows (R4-proven)

    // ---- O += P V (both sides in permuted k-order, swizzled slots) ----
    __builtin_amdgcn_s_setprio(1);
#pragma unroll
    for (int ks = 0; ks < 4; ks++) {
      bf16x8 ap = *(bf16x8*)&Ks[(w * 16 + l15) * 128 + so[ks]];
#pragma unroll
      for (int nt = 0; nt < 4; nt++) {
        bf16x8 bv = *(bf16x8*)&Vs[(nt * 16 + l15) * 128 + so[ks]];
        O[nt] = __builtin_amdgcn_mfma_f32_16x16x32_bf16(ap, bv, O[nt], 0, 0, 0);
      }
    }
    __builtin_amdgcn_s_setprio(0);
    __syncthreads();  // P/V reads done before next staging overwrites
  }

  // ---- final row-sum reduction (once per block) + normalize + store ----
#pragma unroll
  for (int r = 0; r < 4; r++)
#pragma unroll
    for (int m = 1; m < 16; m <<= 1) lsum[r] += __shfl_xor(lsum[r], m, 64);
#pragma unroll
  for (int nt = 0; nt < 4; nt++)
#pragma unroll
    for (int r = 0; r < 4; r++) {
      int row = qt * 64 + w * 16 + lq * 4 + r;
      int col = h * 64 + nt * 16 + l15;
      float val = O[nt][r] / lsum[r];
      aout[((size_t)b * 2048 + row) * 1024 + col] = f2bf(val);
    }
}

// ---------------- host launch ----------------
extern "C" void kernel_launch(void* const* d_in, const int* in_sizes, int n_in,
                              void* d_out, int out_size, void* d_ws, size_t ws_size,
                              hipStream_t stream) {
  const float* x = (const float*)d_in[0];
  const float* context = (const float*)d_in[1];
  const float* g_norm = (const float*)d_in[2];
  const float* null_kv = (const float*)d_in[3];
  const float* Wq = (const float*)d_in[4];
  const float* Wkv = (const float*)d_in[5];
  const float* q_scale = (const float*)d_in[6];
  const float* k_scale = (const float*)d_in[7];
  const float* Wout = (const float*)d_in[8];
  const float* g_out = (const float*)d_in[9];
  float* out = (float*)d_out;

  char* ws = (char*)d_ws;
  u16* xn = (u16*)(ws);                      // 16,777,216 B
  u16* ctxb = (u16*)(ws + 16777216);         // 16,777,216
  u16* wqT = (u16*)(ws + 33554432);          // 2,097,152
  u16* wkvT = (u16*)(ws + 35651584);         // 4,194,304
  u16* woutT = (u16*)(ws + 39845888);        // 2,097,152
  u16* qnb = (u16*)(ws + 41943040);          // 16,777,216
  u16* knb = (u16*)(ws + 58720256);          // 17,825,792
  u16* vtb = (u16*)(ws + 76546048);          // 17,825,792
  u16* vg = (u16*)(ws + 94371840);           // 16,777,216
  float* outg = (float*)(ws + 111149056);    // 33,554,432 -> total 144,703,488
  u16* attn_out = vg;                        // vg fully consumed by v_post

  ln_kernel<true><<<8192, 256, 0, stream>>>(x, g_norm, xn);
  cast_bf16<<<8192, 256, 0, stream>>>(context, ctxb, 2097152);
  transpose_cast<<<dim3(32, 32), 256, 0, stream>>>(Wq, wqT, 1024, 1024);
  transpose_cast<<<dim3(64, 32), 256, 0, stream>>>(Wkv, wkvT, 1024, 2048);
  transpose_cast<<<dim3(32, 32), 256, 0, stream>>>(Wout, woutT, 1024, 1024);
  gemm_bt<2><<<dim3(8, 64), 256, 0, stream>>>(xn, wqT, qnb, 8192, 1024, 1024, q_scale, nullptr);
  gemm_bt<3><<<dim3(16, 64), 256, 0, stream>>>(ctxb, wkvT, knb, 8192, 2048, 1024, k_scale, vg);
  v_post<<<dim3(32, 64), 256, 0, stream>>>(vg, vtb);
  null_tail<<<64, 256, 0, stream>>>(null_kv, k_scale, knb, vtb);
  attn_kernel<<<dim3(32, 64), 256, 0, stream>>>(qnb, knb, vtb, attn_out);
  gemm_bt<0><<<dim3(8, 64), 256, 0, stream>>>(attn_out, woutT, outg, 8192, 1024, 1024, nullptr, nullptr);
  ln_kernel<false><<<8192, 256, 0, stream>>>(outg, g_out, out);
}

// Round 7
// 405.356 us; speedup vs baseline: 1.9088x; 1.0371x over previous
//
#include <hip/hip_runtime.h>

// Problem constants
#define BATCH 4
#define NSEQ 2048
#define MSEQ 2048
#define DIM 1024
#define HEADS 16
#define DHEAD 64
#define INNER 1024
#define KVLEN 2049          // null token + MSEQ
#define KVPAD 2176          // 17 * 128

typedef unsigned short u16;
typedef unsigned int u32;
typedef __bf16 bf16x8 __attribute__((ext_vector_type(8)));
typedef float f32x4 __attribute__((ext_vector_type(4)));

__device__ inline u16 f2bf(float f) {
  u32 u = __builtin_bit_cast(u32, f);
  u = (u + 0x7fffu + ((u >> 16) & 1u)) >> 16;
  return (u16)u;
}
__device__ inline float bf2f(u16 x) {
  return __builtin_bit_cast(float, (u32)x << 16);
}
// packed bf16 convert: lo -> D[15:0], hi -> D[31:16] (RNE)
__device__ inline u32 pk_bf16(float lo, float hi) {
  u32 r;
  asm("v_cvt_pk_bf16_f32 %0, %1, %2" : "=v"(r) : "v"(lo), "v"(hi));
  return r;
}

__device__ __forceinline__ void gld_lds16(const void* g, void* l) {
  __builtin_amdgcn_global_load_lds(
      (const __attribute__((address_space(1))) void*)g,
      (__attribute__((address_space(3))) void*)l, 16, 0, 0);
}

// ---------------- LayerNorm (row of 1024), output bf16 or fp32 ----------------
template <bool OUT_BF16>
__global__ __launch_bounds__(256) void ln_kernel(const float* __restrict__ x,
                                                 const float* __restrict__ g,
                                                 void* __restrict__ out) {
  const int row = blockIdx.x;
  const int t = threadIdx.x;
  const float4 v = ((const float4*)(x + (size_t)row * 1024))[t];
  float sum = v.x + v.y + v.z + v.w;
  float sq = v.x * v.x + v.y * v.y + v.z * v.z + v.w * v.w;
  for (int m = 1; m < 64; m <<= 1) {
    sum += __shfl_xor(sum, m, 64);
    sq += __shfl_xor(sq, m, 64);
  }
  __shared__ float red[8];
  const int w = t >> 6, l = t & 63;
  if (l == 0) { red[w] = sum; red[4 + w] = sq; }
  __syncthreads();
  sum = red[0] + red[1] + red[2] + red[3];
  sq = red[4] + red[5] + red[6] + red[7];
  const float mean = sum * (1.0f / 1024.0f);
  const float var = sq * (1.0f / 1024.0f) - mean * mean;
  const float rstd = rsqrtf(var + 1e-5f);
  const float4 gv = ((const float4*)g)[t];
  float o0 = (v.x - mean) * rstd * gv.x;
  float o1 = (v.y - mean) * rstd * gv.y;
  float o2 = (v.z - mean) * rstd * gv.z;
  float o3 = (v.w - mean) * rstd * gv.w;
  if (OUT_BF16) {
    ushort4 ov;
    ov.x = f2bf(o0); ov.y = f2bf(o1); ov.z = f2bf(o2); ov.w = f2bf(o3);
    ((ushort4*)((u16*)out + (size_t)row * 1024))[t] = ov;
  } else {
    float4 ov;
    ov.x = o0; ov.y = o1; ov.z = o2; ov.w = o3;
    ((float4*)((float*)out + (size_t)row * 1024))[t] = ov;
  }
}

// ---------------- fp32 -> bf16 cast (vectorized by 4) ----------------
__global__ __launch_bounds__(256) void cast_bf16(const float* __restrict__ in,
                                                 u16* __restrict__ out, int n4) {
  int i = blockIdx.x * 256 + threadIdx.x;
  if (i < n4) {
    float4 v = ((const float4*)in)[i];
    ushort4 o;
    o.x = f2bf(v.x); o.y = f2bf(v.y); o.z = f2bf(v.z); o.w = f2bf(v.w);
    ((ushort4*)out)[i] = o;
  }
}

// ---------------- W[K][N] fp32 -> WT[N][K] bf16 (tiled transpose) ----------------
__global__ __launch_bounds__(256) void transpose_cast(const float* __restrict__ W,
                                                      u16* __restrict__ WT, int K, int N) {
  __shared__ float tile[32][33];
  const int tx = threadIdx.x & 31, ty = threadIdx.x >> 5;  // ty 0..7
  const int k0 = blockIdx.y * 32, n0 = blockIdx.x * 32;
  for (int r = ty; r < 32; r += 8) tile[r][tx] = W[(size_t)(k0 + r) * N + n0 + tx];
  __syncthreads();
  for (int r = ty; r < 32; r += 8) WT[(size_t)(n0 + r) * K + k0 + tx] = f2bf(tile[tx][r]);
}

// ---------------- bf16 GEMM: C = A[M][K] @ Bt[N][K]^T ----------------
// MODE 0: fp32 C row-major. MODE 1: bf16 C row-major.
// MODE 2: fused q_post -> l2norm(head)*scale*8, write qn[b,h,n,64].
// MODE 3: fused kv post -> heads 0..15: l2norm*k_scale -> kn[b,h,m+1,64];
//                          heads 16..31: plain bf16 -> aux[row][ (h-16)*64+d ].
template <int MODE>
__global__ __launch_bounds__(256) void gemm_bt(const u16* __restrict__ A,
                                               const u16* __restrict__ Bt,
                                               void* __restrict__ Cv,
                                               int M, int N, int K,
                                               const float* __restrict__ scale,
                                               u16* __restrict__ aux) {
  __shared__ __align__(16) u16 As[128 * 32];
  __shared__ __align__(16) u16 Bs[128 * 32];
  const int t = threadIdx.x;
  const int w = t >> 6, l = t & 63, l15 = l & 15, lq = l >> 4;
  const int m0 = blockIdx.y * 128, n0 = blockIdx.x * 128;
  const int wm = (w >> 1) * 64, wn = (w & 1) * 64;
  const int lr = l >> 2;           // 0..15 row-within-chunk
  const int lo = (l & 3) * 8;      // u16 offset within row: 0,8,16,24
  f32x4 acc[4][4] = {};
  for (int k0 = 0; k0 < K; k0 += 32) {
#pragma unroll
    for (int it = 0; it < 2; it++) {
      const int row = (w * 2 + it) * 16 + lr;   // 0..127
      gld_lds16(&A[(size_t)(m0 + row) * K + k0 + lo], &As[row * 32 + lo]);
      gld_lds16(&Bt[(size_t)(n0 + row) * K + k0 + lo], &Bs[row * 32 + lo]);
    }
    __syncthreads();
    bf16x8 af[4], bfr[4];
#pragma unroll
    for (int i = 0; i < 4; i++) af[i] = *(bf16x8*)&As[(wm + i * 16 + l15) * 32 + lq * 8];
#pragma unroll
    for (int j = 0; j < 4; j++) bfr[j] = *(bf16x8*)&Bs[(wn + j * 16 + l15) * 32 + lq * 8];
#pragma unroll
    for (int i = 0; i < 4; i++)
#pragma unroll
      for (int j = 0; j < 4; j++)
        acc[i][j] = __builtin_amdgcn_mfma_f32_16x16x32_bf16(af[i], bfr[j], acc[i][j], 0, 0, 0);
    __syncthreads();
  }

  if (MODE <= 1) {
#pragma unroll
    for (int i = 0; i < 4; i++)
#pragma unroll
      for (int j = 0; j < 4; j++)
#pragma unroll
        for (int r = 0; r < 4; r++) {
          const size_t off =
              (size_t)(m0 + wm + i * 16 + lq * 4 + r) * N + n0 + wn + j * 16 + l15;
          if (MODE == 1) ((u16*)Cv)[off] = f2bf(acc[i][j][r]);
          else ((float*)Cv)[off] = acc[i][j][r];
        }
    return;
  }

  const int head = (n0 + wn) >> 6;  // wave-uniform
  if (MODE == 3 && head >= 16) {
    // V columns: plain bf16 into compact aux[row][ (head-16)*64 + d ]
#pragma unroll
    for (int i = 0; i < 4; i++)
#pragma unroll
      for (int j = 0; j < 4; j++)
#pragma unroll
        for (int r = 0; r < 4; r++) {
          const int row = m0 + wm + i * 16 + lq * 4 + r;
          aux[(size_t)row * 1024 + (head - 16) * 64 + j * 16 + l15] = f2bf(acc[i][j][r]);
        }
    return;
  }
  // l2norm over the 64-col head + scale (q: *8)
  float sc[4];
#pragma unroll
  for (int j = 0; j < 4; j++) sc[j] = scale[j * 16 + l15];
  const float mul = (MODE == 2) ? 8.0f : 1.0f;
  u16* outp = (u16*)Cv;
#pragma unroll
  for (int i = 0; i < 4; i++)
#pragma unroll
    for (int r = 0; r < 4; r++) {
      float ss = 0.f;
#pragma unroll
      for (int j = 0; j < 4; j++) ss = fmaf(acc[i][j][r], acc[i][j][r], ss);
#pragma unroll
      for (int m = 1; m < 16; m <<= 1) ss += __shfl_xor(ss, m, 64);
      const float inv = mul / fmaxf(sqrtf(ss), 1e-12f);
      const int row = m0 + wm + i * 16 + lq * 4 + r;
      const int b = row >> 11, n = row & 2047;
      const size_t base = (MODE == 2)
          ? (((size_t)b * 16 + head) * 2048 + n) * 64
          : (((size_t)b * 16 + head) * (size_t)KVPAD + n + 1) * 64;
#pragma unroll
      for (int j = 0; j < 4; j++)
        outp[base + j * 16 + l15] = f2bf(acc[i][j][r] * inv * sc[j]);
    }
}

// ---------------- v post: transpose vg[row][h*64+d] -> vt[b,h,64,KVPAD] ----------------
// R7: the KV (column) index is stored k-PERMUTED within each 128-aligned block
// by the bit-permutation matching the in-register P fragments of attn_kernel:
//   forward g(slot): [s6 s5 s4 s3 s2 s1 s0] -> kv-local [s6 s5 s2 s4 s3 s1 s0]
//   inverse slot(a) = (a & 0x63) | ((a & 0x10) >> 2) | ((a & 0x0C) << 1)
// (PV contraction is invariant under a shared k-permutation; the PV A-frag of
// lane (l15,lq), tile m, elem e holds P[q=l15][kv-local = (2m+(e>>2))*16 +
// lq*4 + (e&3)] = g(m*32+lq*8+e).) slot(0)=0 and slot maps {1..127} onto
// {1..127}, so null_tail (null token slot 0, tail zeroing 2049..2175) is
// unchanged. Spot-checked: slot(4)=8, slot(8)=16, slot(16)=4.
__global__ __launch_bounds__(256) void v_post(const u16* __restrict__ vg,
                                              u16* __restrict__ vt) {
  __shared__ u16 tile[64][68];
  const int bh = blockIdx.y, mt = blockIdx.x;
  const int tx = threadIdx.x & 63, ty = threadIdx.x >> 6;
  const int b = bh >> 4, h = bh & 15;
  const int m0 = mt * 64;
  for (int r = ty; r < 64; r += 4)
    tile[tx][r] = vg[(size_t)(b * 2048 + m0 + r) * 1024 + h * 64 + tx];
  __syncthreads();
  const int abs_ = 1 + m0 + tx;
  const int a = abs_ & 127;
  const int slot = (abs_ & ~127) | (a & 0x63) | ((a & 0x10) >> 2) | ((a & 0x0C) << 1);
  for (int d = ty; d < 64; d += 4)
    vt[((size_t)bh * 64 + d) * KVPAD + slot] = tile[d][tx];
}

// ---------------- null token + tail zeroing (256-thread version, R5-verified) ----------------
__global__ __launch_bounds__(256) void null_tail(const float* __restrict__ null_kv,
                                                 const float* __restrict__ k_scale,
                                                 u16* __restrict__ kn, u16* __restrict__ vt) {
  const int bh = blockIdx.x, t = threadIdx.x;
  const int d = t & 63, seg = t >> 6;  // seg 0..3
  if (seg == 0) {  // one full wave: null token (needs 64-lane reduction)
    float nk = null_kv[d];
    float nv = null_kv[64 + d];
    float ss = nk * nk;
    for (int m = 1; m < 64; m <<= 1) ss += __shfl_xor(ss, m, 64);
    float inv = 1.0f / fmaxf(sqrtf(ss), 1e-12f);
    kn[((size_t)bh * KVPAD) * 64 + d] = f2bf(nk * inv * k_scale[d]);
    vt[((size_t)bh * 64 + d) * KVPAD] = f2bf(nv);  // slot(0) == 0
  }
  for (int m = KVLEN + seg; m < KVPAD; m += 4) kn[((size_t)bh * KVPAD + m) * 64 + d] = 0;
  u16* vrow = vt + ((size_t)bh * 64 + d) * KVPAD;
  for (int m = KVLEN + seg; m < KVPAD; m += 4) vrow[m] = 0;
}

// ---------------- flash attention, fixed-max softmax ----------------
// |sim| <= 8 by Cauchy-Schwarz (l2norm'd q,k; scales==1; SCALE=8) -> static max 8.
// R7: SWAPPED QK^T (T12 structure) — compute mfma(K_frag, Q_frag) so D = S^T:
// lane (l15,lq) reg r of tile j holds S[q = base+l15][kv = kt*128+j*16+lq*4+r].
// P = exp(S-8) stays IN REGISTERS: packed via v_cvt_pk_bf16_f32 into the PV
// A-fragments pa[m] (elem e = p[2m+(e>>2)][e&3], matching V's g-permuted rows,
// see v_post). Removes per-wave-kt: 4 ds_writes + 4 ds_reads + 1 barrier
// (R6 was LDS-op bound: 40 ops ~= 109us of 128). LDS ops/wave/kt: 40 -> 32.
// Both MFMA operand lane-layouts (A: row=l15,k=lq*8+e; B: k=lq*8+e,col=l15)
// are the layouts proven by R0-R6 passing kernels; O's output layout is
// unchanged (store identical). lsum: per-lane scalar (q=l15), reduced over lq
// via shfl_xor(16,32), redistributed to (q=lq*4+r) rows via 4 shfl.
// Staging identical to R6: global_load_lds, linear LDS, source-side bank
// swizzle slot' = slot ^ (row&7); fragment reads use so[] = (slot^(l15&7))*8.
// R5 post-mortem: direct-global fragments 3.6x WORSE. R2/R3: 32-q-rows/wave
// variant fails correctness (unlocalized); don't re-attempt without bisection.
__global__ __launch_bounds__(256, 4) void attn_kernel(const u16* __restrict__ qn,
                                                      const u16* __restrict__ kn,
                                                      const u16* __restrict__ vt,
                                                      u16* __restrict__ aout) {
  __shared__ __align__(16) u16 Ks[128 * 64];  // K tile (linear, src-swizzled)
  __shared__ __align__(16) u16 Vs[64 * 128];  // V^T tile (linear, src-swizzled, g-permuted kv)
  const int qt = blockIdx.x, bh = blockIdx.y;
  const int b = bh >> 4, h = bh & 15;
  const int t = threadIdx.x, w = t >> 6, l = t & 63, l15 = l & 15, lq = l >> 4;

  // Q fragments straight from global (loop-invariant); used as MFMA B-operand
  bf16x8 aqf[2];
  {
    const u16* qrow = qn + ((size_t)bh * 2048 + qt * 64 + w * 16 + l15) * 64 + lq * 8;
    aqf[0] = *(const bf16x8*)(qrow);
    aqf[1] = *(const bf16x8*)(qrow + 32);
  }

  // swizzled fragment-read slot offsets (u16): slot' = (ks*4+lq) ^ (l15&7)
  int so[4];
#pragma unroll
  for (int ks = 0; ks < 4; ks++) so[ks] = ((ks * 4 + lq) ^ (l15 & 7)) * 8;

  // staging: per-lane swizzled GLOBAL source, linear LDS dest (base + lane*16)
  const u16* kn_b = kn + (size_t)bh * KVPAD * 64;
  const u16* vt_b = vt + (size_t)bh * 64 * KVPAD;
  const u16* ksrc[4];
  const u16* vsrc[4];
#pragma unroll
  for (int i = 0; i < 4; i++) {
    const int rk = (w * 4 + i) * 8 + (l >> 3);        // K row 0..127
    const int sk = (l & 7) ^ ((l >> 3) & 7);          // swizzled 16B slot (rk&7 == (l>>3)&7)
    ksrc[i] = kn_b + rk * 64 + sk * 8;
    const int rd = (w * 4 + i) * 4 + (l >> 4);        // V d-row 0..63
    const int sv = (l & 15) ^ (rd & 7);               // swizzled 16B slot
    vsrc[i] = vt_b + (size_t)rd * KVPAD + sv * 8;
  }
  u16* kdst = &Ks[w * 2048 + l * 8];  // (w*4+i)*512 + l*8, i via +i*512
  u16* vdst = &Vs[w * 2048 + l * 8];

  f32x4 O[4] = {};
  float lsum = 0.f;
  const float LOG2E = 1.44269504f;
  const float MBIAS = -8.0f * 1.44269504f;  // exp(s-8) = 2^(s*log2e + MBIAS)

  for (int kt = 0; kt < 17; kt++) {
    // ---- stage K (128x64) and V^T (64x128) via global_load_lds, src-swizzled ----
#pragma unroll
    for (int i = 0; i < 4; i++) {
      gld_lds16(ksrc[i] + kt * 8192, kdst + i * 512);
      gld_lds16(vsrc[i] + kt * 128, vdst + i * 512);
    }
    __syncthreads();  // compiler drains vmcnt before s_barrier

    // ---- S^T = K Q^T (swapped): St[j] lane(l15,lq) reg r = S[q=l15][j*16+lq*4+r] ----
    f32x4 St[8] = {};
    __builtin_amdgcn_s_setprio(1);
#pragma unroll
    for (int ks = 0; ks < 2; ks++)
#pragma unroll
      for (int j = 0; j < 8; j++) {
        bf16x8 ak = *(bf16x8*)&Ks[(j * 16 + l15) * 64 + so[ks]];
        St[j] = __builtin_amdgcn_mfma_f32_16x16x32_bf16(ak, aqf[ks], St[j], 0, 0, 0);
      }
    __builtin_amdgcn_s_setprio(0);

    // ---- P = exp(S - 8) in registers; lsum (per-lane, q=l15); pack pa frags ----
    const bool last = (kt == 16);
    float p[8][4];
#pragma unroll
    for (int j = 0; j < 8; j++)
#pragma unroll
      for (int r = 0; r < 4; r++) {
        float pv = __builtin_amdgcn_exp2f(fmaf(St[j][r], LOG2E, MBIAS));
        if (last && ((j << 4) + (lq << 2) + r) != 0) pv = 0.f;  // only kv 2048 valid
        lsum += pv;
        p[j][r] = pv;
      }
    bf16x8 pa[4];
#pragma unroll
    for (int m = 0; m < 4; m++) {
      uint4 pw;
      pw.x = pk_bf16(p[2 * m][0], p[2 * m][1]);
      pw.y = pk_bf16(p[2 * m][2], p[2 * m][3]);
      pw.z = pk_bf16(p[2 * m + 1][0], p[2 * m + 1][1]);
      pw.w = pk_bf16(p[2 * m + 1][2], p[2 * m + 1][3]);
      pa[m] = __builtin_bit_cast(bf16x8, pw);
    }

    // ---- O += P V (A = pa registers; V rows g-permuted to match) ----
    __builtin_amdgcn_s_setprio(1);
#pragma unroll
    for (int m = 0; m < 4; m++)
#pragma unroll
      for (int nt = 0; nt < 4; nt++) {
        bf16x8 bv = *(bf16x8*)&Vs[(nt * 16 + l15) * 128 + so[m]];
        O[nt] = __builtin_amdgcn_mfma_f32_16x16x32_bf16(pa[m], bv, O[nt], 0, 0, 0);
      }
    __builtin_amdgcn_s_setprio(0);
    __syncthreads();  // K/V reads done before next staging overwrites
  }

  // ---- lsum: reduce over lq-groups, redistribute to (q = lq*4+r) rows ----
  lsum += __shfl_xor(lsum, 16, 64);
  lsum += __shfl_xor(lsum, 32, 64);  // all lanes now hold total for q = l15
  float ls[4];
#pragma unroll
  for (int r = 0; r < 4; r++) ls[r] = __shfl(lsum, lq * 4 + r, 64);

  // ---- normalize + store (O layout identical to R6) ----
#pragma unroll
  for (int nt = 0; nt < 4; nt++)
#pragma unroll
    for (int r = 0; r < 4; r++) {
      int row = qt * 64 + w * 16 + lq * 4 + r;
      int col = h * 64 + nt * 16 + l15;
      float val = O[nt][r] / ls[r];
      aout[((size_t)b * 2048 + row) * 1024 + col] = f2bf(val);
    }
}

// ---------------- host launch ----------------
extern "C" void kernel_launch(void* const* d_in, const int* in_sizes, int n_in,
                              void* d_out, int out_size, void* d_ws, size_t ws_size,
                              hipStream_t stream) {
  const float* x = (const float*)d_in[0];
  const float* context = (const float*)d_in[1];
  const float* g_norm = (const float*)d_in[2];
  const float* null_kv = (const float*)d_in[3];
  const float* Wq = (const float*)d_in[4];
  const float* Wkv = (const float*)d_in[5];
  const float* q_scale = (const float*)d_in[6];
  const float* k_scale = (const float*)d_in[7];
  const float* Wout = (const float*)d_in[8];
  const float* g_out = (const float*)d_in[9];
  float* out = (float*)d_out;

  char* ws = (char*)d_ws;
  u16* xn = (u16*)(ws);                      // 16,777,216 B
  u16* ctxb = (u16*)(ws + 16777216);         // 16,777,216
  u16* wqT = (u16*)(ws + 33554432);          // 2,097,152
  u16* wkvT = (u16*)(ws + 35651584);         // 4,194,304
  u16* woutT = (u16*)(ws + 39845888);        // 2,097,152
  u16* qnb = (u16*)(ws + 41943040);          // 16,777,216
  u16* knb = (u16*)(ws + 58720256);          // 17,825,792
  u16* vtb = (u16*)(ws + 76546048);          // 17,825,792
  u16* vg = (u16*)(ws + 94371840);           // 16,777,216
  float* outg = (float*)(ws + 111149056);    // 33,554,432 -> total 144,703,488
  u16* attn_out = vg;                        // vg fully consumed by v_post

  ln_kernel<true><<<8192, 256, 0, stream>>>(x, g_norm, xn);
  cast_bf16<<<8192, 256, 0, stream>>>(context, ctxb, 2097152);
  transpose_cast<<<dim3(32, 32), 256, 0, stream>>>(Wq, wqT, 1024, 1024);
  transpose_cast<<<dim3(64, 32), 256, 0, stream>>>(Wkv, wkvT, 1024, 2048);
  transpose_cast<<<dim3(32, 32), 256, 0, stream>>>(Wout, woutT, 1024, 1024);
  gemm_bt<2><<<dim3(8, 64), 256, 0, stream>>>(xn, wqT, qnb, 8192, 1024, 1024, q_scale, nullptr);
  gemm_bt<3><<<dim3(16, 64), 256, 0, stream>>>(ctxb, wkvT, knb, 8192, 2048, 1024, k_scale, vg);
  v_post<<<dim3(32, 64), 256, 0, stream>>>(vg, vtb);
  null_tail<<<64, 256, 0, stream>>>(null_kv, k_scale, knb, vtb);
  attn_kernel<<<dim3(32, 64), 256, 0, stream>>>(qnb, knb, vtb, attn_out);
  gemm_bt<0><<<dim3(8, 64), 256, 0, stream>>>(attn_out, woutT, outg, 8192, 1024, 1024, nullptr, nullptr);
  ln_kernel<false><<<8192, 256, 0, stream>>>(outg, g_out, out);
}